// Round 1
// baseline (564.409 us; speedup 1.0000x reference)
//
#include <hip/hip_runtime.h>
#include <hip/hip_bf16.h>

// Problem constants
#define BB 2
#define SS 2048
#define DD 1024
#define HH 16
#define DHD 64

typedef __attribute__((ext_vector_type(8))) __bf16 bf16x8;
typedef __attribute__((ext_vector_type(4))) __bf16 bf16x4;
typedef __attribute__((ext_vector_type(4))) float f32x4;

__device__ __forceinline__ f32x4 mfma16(bf16x8 a, bf16x8 b, f32x4 c) {
  return __builtin_amdgcn_mfma_f32_16x16x32_bf16(a, b, c, 0, 0, 0);
}

// ---------------------------------------------------------------- cast x -> bf16
__global__ __launch_bounds__(256) void cast_x_kernel(const float* __restrict__ in,
                                                     __bf16* __restrict__ out, int n4) {
  int i = blockIdx.x * 256 + threadIdx.x;
  if (i >= n4) return;
  float4 f = ((const float4*)in)[i];
  bf16x4 o;
  o[0] = (__bf16)f.x; o[1] = (__bf16)f.y; o[2] = (__bf16)f.z; o[3] = (__bf16)f.w;
  *(bf16x4*)(out + (size_t)i * 4) = o;
}

// --------------------------------------------- W [K,N] fp32 -> WT [N,K] bf16
__global__ __launch_bounds__(256) void wtrans_kernel(const float* __restrict__ W,
                                                     __bf16* __restrict__ WT) {
  __shared__ __bf16 t[64][65];  // odd stride: scalar access both phases
  int c0 = blockIdx.x * 64, r0 = blockIdx.y * 64;
  int tid = threadIdx.x;
  {
    int rr = tid >> 4;        // 0..15
    int cg = tid & 15;        // 16 groups of 4 cols
#pragma unroll
    for (int it = 0; it < 4; ++it) {
      int r = rr + it * 16;
      float4 f = *(const float4*)(W + (size_t)(r0 + r) * DD + c0 + cg * 4);
      t[r][cg * 4 + 0] = (__bf16)f.x;
      t[r][cg * 4 + 1] = (__bf16)f.y;
      t[r][cg * 4 + 2] = (__bf16)f.z;
      t[r][cg * 4 + 3] = (__bf16)f.w;
    }
  }
  __syncthreads();
  {
    int sg = tid & 7;
#pragma unroll
    for (int it = 0; it < 2; ++it) {
      int wc = (tid >> 3) + it * 32;
      __bf16 tmp[8];
#pragma unroll
      for (int e = 0; e < 8; ++e) tmp[e] = t[sg * 8 + e][wc];
      bf16x8 o;
#pragma unroll
      for (int e = 0; e < 8; ++e) o[e] = tmp[e];
      *(bf16x8*)(WT + (size_t)(c0 + wc) * DD + r0 + sg * 8) = o;
    }
  }
}

// --------------------------- v [B,S,H*DH] bf16 -> vt [B,H,DH,S] bf16
__global__ __launch_bounds__(256) void vtrans_kernel(const __bf16* __restrict__ v,
                                                     __bf16* __restrict__ vt) {
  __shared__ __attribute__((aligned(16))) __bf16 t[64][72];
  int s0 = blockIdx.x * 64;
  int h = blockIdx.y, b = blockIdx.z;
  int tid = threadIdx.x;
  {
    int row = tid >> 3, cg = tid & 7;  // 32 rows/iter, 8 col groups of 8
#pragma unroll
    for (int it = 0; it < 2; ++it) {
      int r = row + it * 32;
      bf16x8 val = *(const bf16x8*)(v + ((size_t)(b * SS + s0 + r)) * DD + h * DHD + cg * 8);
      *(bf16x8*)(&t[r][cg * 8]) = val;
    }
  }
  __syncthreads();
  {
    int sg = tid & 7;
#pragma unroll
    for (int it = 0; it < 2; ++it) {
      int d = (tid >> 3) + it * 32;
      __bf16 tmp[8];
#pragma unroll
      for (int e = 0; e < 8; ++e) tmp[e] = t[sg * 8 + e][d];
      bf16x8 o;
#pragma unroll
      for (int e = 0; e < 8; ++e) o[e] = tmp[e];
      *(bf16x8*)(vt + ((size_t)((b * HH + h) * DHD + d)) * SS + s0 + sg * 8) = o;
    }
  }
}

// ---------------------------------------------------------------- GEMM
// C[M,N] = A[M,K] @ BT[N,K]^T. A,BT bf16, fp32 MFMA accum.
// wave tile 32x32, block 2x2 waves => 64x64. grid (M/64, N/64).
template <bool F32OUT>
__global__ __launch_bounds__(256) void gemm_bt_kernel(
    const __bf16* __restrict__ A, const __bf16* __restrict__ BT,
    float* __restrict__ Cf, __bf16* __restrict__ Cb,
    const float* __restrict__ bias, int M, int N, int K) {
  int lane = threadIdx.x & 63;
  int wave = threadIdx.x >> 6;
  int lr = lane & 15, lg = lane >> 4;
  int m0 = blockIdx.x * 64 + (wave >> 1) * 32;
  int n0 = blockIdx.y * 64 + (wave & 1) * 32;
  const __bf16* a0p = A + (size_t)(m0 + lr) * K + 8 * lg;
  const __bf16* a1p = a0p + (size_t)16 * K;
  const __bf16* b0p = BT + (size_t)(n0 + lr) * K + 8 * lg;
  const __bf16* b1p = b0p + (size_t)16 * K;
  f32x4 acc00 = {0.f, 0.f, 0.f, 0.f};
  f32x4 acc01 = acc00, acc10 = acc00, acc11 = acc00;
#pragma unroll 4
  for (int k = 0; k < K; k += 32) {
    bf16x8 a0 = *(const bf16x8*)(a0p + k);
    bf16x8 a1 = *(const bf16x8*)(a1p + k);
    bf16x8 b0 = *(const bf16x8*)(b0p + k);
    bf16x8 b1 = *(const bf16x8*)(b1p + k);
    acc00 = mfma16(a0, b0, acc00);
    acc01 = mfma16(a0, b1, acc01);
    acc10 = mfma16(a1, b0, acc10);
    acc11 = mfma16(a1, b1, acc11);
  }
  // D layout: col = lane&15, row = 4*(lane>>4) + reg
#define STORE_FRAG(ACC, MI, NI)                                        \
  {                                                                    \
    int cc = n0 + 16 * (NI) + lr;                                      \
    _Pragma("unroll") for (int r = 0; r < 4; ++r) {                    \
      int rr = m0 + 16 * (MI) + 4 * lg + r;                            \
      if constexpr (F32OUT) {                                          \
        Cf[(size_t)rr * N + cc] = ACC[r] + bias[cc];                   \
      } else {                                                         \
        Cb[(size_t)rr * N + cc] = (__bf16)ACC[r];                      \
      }                                                                \
    }                                                                  \
  }
  STORE_FRAG(acc00, 0, 0)
  STORE_FRAG(acc01, 0, 1)
  STORE_FRAG(acc10, 1, 0)
  STORE_FRAG(acc11, 1, 1)
#undef STORE_FRAG
}

// ---------------------------------------------------------------- attention
// grid (S/64, H, B), 256 threads = 4 waves, each wave owns 16 q rows.
// Q,K: [B,S,H*DH] bf16 ; VT: [B,H,DH,S] bf16 ; mask: [B,S] fp32 ; out ctx bf16 [B,S,H*DH]
__global__ __launch_bounds__(256) void attn_kernel(
    const __bf16* __restrict__ Q, const __bf16* __restrict__ Kk,
    const __bf16* __restrict__ VT, const float* __restrict__ mask,
    __bf16* __restrict__ ctxb) {
  int h = blockIdx.y, b = blockIdx.z;
  int tid = threadIdx.x;
  int wave = tid >> 6, lane = tid & 63;
  int lr = lane & 15, lg = lane >> 4;

  __shared__ __attribute__((aligned(16))) float maskS[SS];
  __shared__ __attribute__((aligned(16))) __bf16 pS[4][16][72];

  for (int i = tid; i < SS / 4; i += 256)
    ((float4*)maskS)[i] = ((const float4*)(mask + (size_t)b * SS))[i];
  __syncthreads();

  int q0 = blockIdx.x * 64 + wave * 16;
  const __bf16* qp = Q + ((size_t)(b * SS) + q0 + lr) * DD + h * DHD;
  bf16x8 qa0 = *(const bf16x8*)(qp + 8 * lg);
  bf16x8 qa1 = *(const bf16x8*)(qp + 32 + 8 * lg);

  const __bf16* kbase = Kk + (size_t)(b * SS) * DD + h * DHD + 8 * lg;
  const __bf16* vbase = VT + ((size_t)(b * HH + h) * DHD) * SS + 8 * lg;

  float m_run[4] = {-1e30f, -1e30f, -1e30f, -1e30f};
  float l_run[4] = {0.f, 0.f, 0.f, 0.f};
  f32x4 zero = {0.f, 0.f, 0.f, 0.f};
  f32x4 ctx0 = zero, ctx1 = zero, ctx2 = zero, ctx3 = zero;
  const float scale = 0.03125f;  // 1/sqrt(1024)

  for (int kb = 0; kb < SS; kb += 64) {
    // ---- QK^T for 64 keys: 4 chunks of 16
    f32x4 s0 = zero, s1 = zero, s2 = zero, s3 = zero;
    {
      const __bf16* kp = kbase + (size_t)(kb + lr) * DD;
      s0 = mfma16(qa0, *(const bf16x8*)(kp), s0);
      s0 = mfma16(qa1, *(const bf16x8*)(kp + 32), s0);
      kp += (size_t)16 * DD;
      s1 = mfma16(qa0, *(const bf16x8*)(kp), s1);
      s1 = mfma16(qa1, *(const bf16x8*)(kp + 32), s1);
      kp += (size_t)16 * DD;
      s2 = mfma16(qa0, *(const bf16x8*)(kp), s2);
      s2 = mfma16(qa1, *(const bf16x8*)(kp + 32), s2);
      kp += (size_t)16 * DD;
      s3 = mfma16(qa0, *(const bf16x8*)(kp), s3);
      s3 = mfma16(qa1, *(const bf16x8*)(kp + 32), s3);
    }
    // ---- scale + mask; per-lane scores: row q = 4*lg + r, col key = kb + 16f + lr
    float mk0 = maskS[kb + lr];
    float mk1 = maskS[kb + 16 + lr];
    float mk2 = maskS[kb + 32 + lr];
    float mk3 = maskS[kb + 48 + lr];
    float sv[4][4];  // [f][r], fully unrolled -> registers
#pragma unroll
    for (int r = 0; r < 4; ++r) {
      sv[0][r] = s0[r] * scale + mk0;
      sv[1][r] = s1[r] * scale + mk1;
      sv[2][r] = s2[r] * scale + mk2;
      sv[3][r] = s3[r] * scale + mk3;
    }
    // ---- row max across 16 lanes of the group
    float rmax[4];
#pragma unroll
    for (int r = 0; r < 4; ++r)
      rmax[r] = fmaxf(fmaxf(sv[0][r], sv[1][r]), fmaxf(sv[2][r], sv[3][r]));
#pragma unroll
    for (int off = 1; off < 16; off <<= 1) {
#pragma unroll
      for (int r = 0; r < 4; ++r)
        rmax[r] = fmaxf(rmax[r], __shfl_xor(rmax[r], off, 64));
    }
    float alpha[4], rsum[4];
#pragma unroll
    for (int r = 0; r < 4; ++r) {
      float mnew = fmaxf(m_run[r], rmax[r]);
      alpha[r] = __expf(m_run[r] - mnew);
      m_run[r] = mnew;
      float p0 = __expf(sv[0][r] - mnew);
      float p1 = __expf(sv[1][r] - mnew);
      float p2 = __expf(sv[2][r] - mnew);
      float p3 = __expf(sv[3][r] - mnew);
      sv[0][r] = p0; sv[1][r] = p1; sv[2][r] = p2; sv[3][r] = p3;
      rsum[r] = (p0 + p1) + (p2 + p3);
    }
#pragma unroll
    for (int off = 1; off < 16; off <<= 1) {
#pragma unroll
      for (int r = 0; r < 4; ++r)
        rsum[r] += __shfl_xor(rsum[r], off, 64);
    }
#pragma unroll
    for (int r = 0; r < 4; ++r) {
      l_run[r] = l_run[r] * alpha[r] + rsum[r];
      ctx0[r] *= alpha[r];
      ctx1[r] *= alpha[r];
      ctx2[r] *= alpha[r];
      ctx3[r] *= alpha[r];
    }
    // ---- P (bf16) -> wave-private LDS, re-read as PV A-fragments
#pragma unroll
    for (int f = 0; f < 4; ++f) {
#pragma unroll
      for (int r = 0; r < 4; ++r)
        pS[wave][4 * lg + r][16 * f + lr] = (__bf16)sv[f][r];
    }
    bf16x8 pa0 = *(const bf16x8*)(&pS[wave][lr][8 * lg]);
    bf16x8 pa1 = *(const bf16x8*)(&pS[wave][lr][32 + 8 * lg]);
    // ---- PV: ctx[c] += P[16x64] @ V[kb..kb+63][16c..16c+15]
    {
      const __bf16* vp = vbase + (size_t)lr * SS + kb;
      ctx0 = mfma16(pa0, *(const bf16x8*)(vp), ctx0);
      ctx0 = mfma16(pa1, *(const bf16x8*)(vp + 32), ctx0);
      vp += (size_t)16 * SS;
      ctx1 = mfma16(pa0, *(const bf16x8*)(vp), ctx1);
      ctx1 = mfma16(pa1, *(const bf16x8*)(vp + 32), ctx1);
      vp += (size_t)16 * SS;
      ctx2 = mfma16(pa0, *(const bf16x8*)(vp), ctx2);
      ctx2 = mfma16(pa1, *(const bf16x8*)(vp + 32), ctx2);
      vp += (size_t)16 * SS;
      ctx3 = mfma16(pa0, *(const bf16x8*)(vp), ctx3);
      ctx3 = mfma16(pa1, *(const bf16x8*)(vp + 32), ctx3);
    }
  }
  // ---- epilogue: divide by l, store bf16
  __bf16* op = ctxb + ((size_t)(b * SS) + q0 + 4 * lg) * DD + h * DHD + lr;
#pragma unroll
  for (int r = 0; r < 4; ++r) {
    float inv = 1.0f / l_run[r];
    op[(size_t)r * DD + 0]  = (__bf16)(ctx0[r] * inv);
    op[(size_t)r * DD + 16] = (__bf16)(ctx1[r] * inv);
    op[(size_t)r * DD + 32] = (__bf16)(ctx2[r] * inv);
    op[(size_t)r * DD + 48] = (__bf16)(ctx3[r] * inv);
  }
}

// ---------------------------------------------------------------- launcher
extern "C" void kernel_launch(void* const* d_in, const int* in_sizes, int n_in,
                              void* d_out, int out_size, void* d_ws, size_t ws_size,
                              hipStream_t stream) {
  const float* x    = (const float*)d_in[0];
  const float* mask = (const float*)d_in[1];
  const float* Wq   = (const float*)d_in[2];
  const float* Wk   = (const float*)d_in[3];
  const float* Wv   = (const float*)d_in[4];
  const float* Wo   = (const float*)d_in[5];
  const float* bo   = (const float*)d_in[6];
  float* out = (float*)d_out;

  char* ws = (char*)d_ws;
  const size_t MB = 1024 * 1024;
  __bf16* xb   = (__bf16*)(ws + 0);        // 8 MB (also reused as ctxb later)
  __bf16* WqT  = (__bf16*)(ws + 8 * MB);   // 2 MB
  __bf16* WkT  = (__bf16*)(ws + 10 * MB);  // 2 MB
  __bf16* WvT  = (__bf16*)(ws + 12 * MB);  // 2 MB
  __bf16* WoT  = (__bf16*)(ws + 14 * MB);  // 2 MB
  __bf16* qb   = (__bf16*)(ws + 16 * MB);  // 8 MB
  __bf16* kbuf = (__bf16*)(ws + 24 * MB);  // 8 MB
  __bf16* vb   = (__bf16*)(ws + 32 * MB);  // 8 MB
  __bf16* vtb  = (__bf16*)(ws + 40 * MB);  // 8 MB
  __bf16* ctxb = xb;                       // alias: x_bf16 dead after V projection

  const int M = BB * SS;  // 4096
  // 1) casts / transposes of weights
  cast_x_kernel<<<(M * DD) / 1024, 256, 0, stream>>>(x, xb, (M * DD) / 4);
  dim3 gw(DD / 64, DD / 64);
  wtrans_kernel<<<gw, 256, 0, stream>>>(Wq, WqT);
  wtrans_kernel<<<gw, 256, 0, stream>>>(Wk, WkT);
  wtrans_kernel<<<gw, 256, 0, stream>>>(Wv, WvT);
  wtrans_kernel<<<gw, 256, 0, stream>>>(Wo, WoT);
  // 2) QKV projections (bf16 out)
  dim3 gg(M / 64, DD / 64);
  gemm_bt_kernel<false><<<gg, 256, 0, stream>>>(xb, WqT, nullptr, qb, nullptr, M, DD, DD);
  gemm_bt_kernel<false><<<gg, 256, 0, stream>>>(xb, WkT, nullptr, kbuf, nullptr, M, DD, DD);
  gemm_bt_kernel<false><<<gg, 256, 0, stream>>>(xb, WvT, nullptr, vb, nullptr, M, DD, DD);
  // 3) transpose V per head
  dim3 gt(SS / 64, HH, BB);
  vtrans_kernel<<<gt, 256, 0, stream>>>(vb, vtb);
  // 4) attention (writes ctx bf16 over xb region)
  dim3 ga(SS / 64, HH, BB);
  attn_kernel<<<ga, 256, 0, stream>>>(qb, kbuf, vtb, mask, ctxb);
  // 5) output projection (fp32 out + bias)
  gemm_bt_kernel<true><<<gg, 256, 0, stream>>>(ctxb, WoT, out, nullptr, bo, M, DD, DD);
}

// Round 2
// 298.302 us; speedup vs baseline: 1.8921x; 1.8921x over previous
//
#include <hip/hip_runtime.h>
#include <hip/hip_bf16.h>

// Problem constants
#define BB 2
#define SS 2048
#define DD 1024
#define HH 16
#define DHD 64

typedef __attribute__((ext_vector_type(8))) __bf16 bf16x8;
typedef __attribute__((ext_vector_type(4))) __bf16 bf16x4;
typedef __attribute__((ext_vector_type(4))) float f32x4;

__device__ __forceinline__ f32x4 mfma16(bf16x8 a, bf16x8 b, f32x4 c) {
  return __builtin_amdgcn_mfma_f32_16x16x32_bf16(a, b, c, 0, 0, 0);
}

// async global->LDS, 16B per lane; lds ptr must be wave-uniform (HW adds lane*16)
__device__ __forceinline__ void gload_lds16(const void* g, void* l) {
  __builtin_amdgcn_global_load_lds((__attribute__((address_space(1))) const void*)g,
                                   (__attribute__((address_space(3))) void*)l, 16, 0, 0);
}

// ---------------------------------------------------------------- cast x -> bf16
__global__ __launch_bounds__(256) void cast_x_kernel(const float* __restrict__ in,
                                                     __bf16* __restrict__ out, int n4) {
  int i = blockIdx.x * 256 + threadIdx.x;
  if (i >= n4) return;
  float4 f = ((const float4*)in)[i];
  bf16x4 o;
  o[0] = (__bf16)f.x; o[1] = (__bf16)f.y; o[2] = (__bf16)f.z; o[3] = (__bf16)f.w;
  *(bf16x4*)(out + (size_t)i * 4) = o;
}

// --------------------------------------------- W [K,N] fp32 -> WT [N,K] bf16
__global__ __launch_bounds__(256) void wtrans_kernel(const float* __restrict__ W,
                                                     __bf16* __restrict__ WT) {
  __shared__ __bf16 t[64][65];
  int c0 = blockIdx.x * 64, r0 = blockIdx.y * 64;
  int tid = threadIdx.x;
  {
    int rr = tid >> 4;
    int cg = tid & 15;
#pragma unroll
    for (int it = 0; it < 4; ++it) {
      int r = rr + it * 16;
      float4 f = *(const float4*)(W + (size_t)(r0 + r) * DD + c0 + cg * 4);
      t[r][cg * 4 + 0] = (__bf16)f.x;
      t[r][cg * 4 + 1] = (__bf16)f.y;
      t[r][cg * 4 + 2] = (__bf16)f.z;
      t[r][cg * 4 + 3] = (__bf16)f.w;
    }
  }
  __syncthreads();
  {
    int sg = tid & 7;
#pragma unroll
    for (int it = 0; it < 2; ++it) {
      int wc = (tid >> 3) + it * 32;
      __bf16 tmp[8];
#pragma unroll
      for (int e = 0; e < 8; ++e) tmp[e] = t[sg * 8 + e][wc];
      bf16x8 o;
#pragma unroll
      for (int e = 0; e < 8; ++e) o[e] = tmp[e];
      *(bf16x8*)(WT + (size_t)(c0 + wc) * DD + r0 + sg * 8) = o;
    }
  }
}

// --------------------------- v [B,S,H*DH] bf16 -> vt [B,H,DH,S] bf16
__global__ __launch_bounds__(256) void vtrans_kernel(const __bf16* __restrict__ v,
                                                     __bf16* __restrict__ vt) {
  __shared__ __attribute__((aligned(16))) __bf16 t[64][72];
  int s0 = blockIdx.x * 64;
  int h = blockIdx.y, b = blockIdx.z;
  int tid = threadIdx.x;
  {
    int row = tid >> 3, cg = tid & 7;
#pragma unroll
    for (int it = 0; it < 2; ++it) {
      int r = row + it * 32;
      bf16x8 val = *(const bf16x8*)(v + ((size_t)(b * SS + s0 + r)) * DD + h * DHD + cg * 8);
      *(bf16x8*)(&t[r][cg * 8]) = val;
    }
  }
  __syncthreads();
  {
    int sg = tid & 7;
#pragma unroll
    for (int it = 0; it < 2; ++it) {
      int d = (tid >> 3) + it * 32;
      __bf16 tmp[8];
#pragma unroll
      for (int e = 0; e < 8; ++e) tmp[e] = t[sg * 8 + e][d];
      bf16x8 o;
#pragma unroll
      for (int e = 0; e < 8; ++e) o[e] = tmp[e];
      *(bf16x8*)(vt + ((size_t)((b * HH + h) * DHD + d)) * SS + s0 + sg * 8) = o;
    }
  }
}

// ---------------------------------------------------------------- GEMM (m97-style)
// C[M,N] = A[M,K] @ BT[N,K]^T. 128x128 tile, BK=32, 4 waves x (64x64),
// global_load_lds staging, double-buffered, 2-bit XOR swizzle on 64B LDS rows.
template <bool F32OUT>
__global__ __launch_bounds__(256, 2) void gemm128_kernel(
    const __bf16* __restrict__ A, const __bf16* __restrict__ BT,
    float* __restrict__ Cf, __bf16* __restrict__ Cb,
    const float* __restrict__ bias, int M, int N, int K) {
  __shared__ __bf16 As[2][128 * 32];
  __shared__ __bf16 Bs[2][128 * 32];
  int tid = threadIdx.x;
  int lane = tid & 63, wave = tid >> 6;
  int lr = lane & 15, lg = lane >> 4;
  int wr = wave >> 1, wc = wave & 1;
  int m0 = blockIdx.x * 128, n0 = blockIdx.y * 128;

  // staging geometry: tile [128][32] bf16 (64B rows), 2 issues/thread, lane adds 16B
  int o0 = wave * 1024 + lane * 16;
  int r0i = o0 >> 6, s0i = ((o0 >> 4) & 3) ^ (r0i & 3);
  int o1 = o0 + 4096;
  int r1i = o1 >> 6, s1i = ((o1 >> 4) & 3) ^ (r1i & 3);

  const __bf16* Ag0 = A + (size_t)(m0 + r0i) * K + s0i * 8;
  const __bf16* Ag1 = A + (size_t)(m0 + r1i) * K + s1i * 8;
  const __bf16* Bg0 = BT + (size_t)(n0 + r0i) * K + s0i * 8;
  const __bf16* Bg1 = BT + (size_t)(n0 + r1i) * K + s1i * 8;
  int lb0 = wave * 1024;      // wave-uniform LDS byte base, issue 0
  int lb1 = wave * 1024 + 4096;

  f32x4 acc[4][4];
#pragma unroll
  for (int m = 0; m < 4; ++m)
#pragma unroll
    for (int n = 0; n < 4; ++n) acc[m][n] = (f32x4){0.f, 0.f, 0.f, 0.f};

  // prologue: stage k=0 into buf 0
  gload_lds16(Ag0, (char*)As[0] + lb0);
  gload_lds16(Ag1, (char*)As[0] + lb1);
  gload_lds16(Bg0, (char*)Bs[0] + lb0);
  gload_lds16(Bg1, (char*)Bs[0] + lb1);
  __syncthreads();

  int NK = K >> 5;
  for (int it = 0; it < NK; ++it) {
    int cur = it & 1;
    if (it + 1 < NK) {
      int ko = (it + 1) * 32;
      gload_lds16(Ag0 + ko, (char*)As[cur ^ 1] + lb0);
      gload_lds16(Ag1 + ko, (char*)As[cur ^ 1] + lb1);
      gload_lds16(Bg0 + ko, (char*)Bs[cur ^ 1] + lb0);
      gload_lds16(Bg1 + ko, (char*)Bs[cur ^ 1] + lb1);
    }
    const char* Ab = (const char*)As[cur];
    const char* Bb = (const char*)Bs[cur];
    bf16x8 af[4], bfr[4];
#pragma unroll
    for (int m = 0; m < 4; ++m) {
      int row = wr * 64 + m * 16 + lr;
      af[m] = *(const bf16x8*)(Ab + row * 64 + ((lg ^ (row & 3)) << 4));
    }
#pragma unroll
    for (int n = 0; n < 4; ++n) {
      int row = wc * 64 + n * 16 + lr;
      bfr[n] = *(const bf16x8*)(Bb + row * 64 + ((lg ^ (row & 3)) << 4));
    }
#pragma unroll
    for (int m = 0; m < 4; ++m)
#pragma unroll
      for (int n = 0; n < 4; ++n) acc[m][n] = mfma16(af[m], bfr[n], acc[m][n]);
    __syncthreads();
  }

  // epilogue: D layout col = lane&15, row = 4*(lane>>4)+reg
#pragma unroll
  for (int m = 0; m < 4; ++m) {
#pragma unroll
    for (int n = 0; n < 4; ++n) {
      int cc = n0 + wc * 64 + n * 16 + lr;
#pragma unroll
      for (int r = 0; r < 4; ++r) {
        int rr = m0 + wr * 64 + m * 16 + 4 * lg + r;
        if constexpr (F32OUT) {
          Cf[(size_t)rr * N + cc] = acc[m][n][r] + bias[cc];
        } else {
          Cb[(size_t)rr * N + cc] = (__bf16)acc[m][n][r];
        }
      }
    }
  }
}

// ---------------------------------------------------------------- attention
// grid (S/128, H, B), 4 waves, each wave owns 32 q rows. K/V tiles (64x64)
// LDS-staged via global_load_lds (shared by all waves), double-buffered,
// 3-bit XOR swizzle on 128B rows. P via wave-private padded LDS.
__global__ __launch_bounds__(256, 2) void attn_kernel(
    const __bf16* __restrict__ Q, const __bf16* __restrict__ Kk,
    const __bf16* __restrict__ VT, const float* __restrict__ mask,
    __bf16* __restrict__ ctxb) {
  __shared__ __bf16 Ks[2][64 * 64];
  __shared__ __bf16 Vs[2][64 * 64];
  __shared__ __attribute__((aligned(16))) __bf16 pS[4][32][72];
  __shared__ __attribute__((aligned(16))) float maskS[SS];

  int h = blockIdx.y, b = blockIdx.z;
  int tid = threadIdx.x;
  int wave = tid >> 6, lane = tid & 63;
  int lr = lane & 15, lg = lane >> 4;

  for (int i = tid; i < SS / 4; i += 256)
    ((float4*)maskS)[i] = ((const float4*)(mask + (size_t)b * SS))[i];

  int q0 = blockIdx.x * 128 + wave * 32;
  const __bf16* qp = Q + ((size_t)(b * SS) + q0 + lr) * DD + h * DHD;
  bf16x8 qa[2][2];
#pragma unroll
  for (int m = 0; m < 2; ++m)
#pragma unroll
    for (int kc = 0; kc < 2; ++kc)
      qa[m][kc] = *(const bf16x8*)(qp + (size_t)m * 16 * DD + kc * 32 + 8 * lg);

  // staging geometry: 64x64 bf16 tile (128B rows), 2 issues/thread
  int o0 = wave * 1024 + lane * 16;
  int r0i = o0 >> 7, s0i = ((o0 >> 4) & 7) ^ (r0i & 7);
  int o1 = o0 + 4096;
  int r1i = o1 >> 7, s1i = ((o1 >> 4) & 7) ^ (r1i & 7);
  int lb0 = wave * 1024, lb1 = wave * 1024 + 4096;

  const __bf16* Kg = Kk + ((size_t)(b * SS)) * DD + h * DHD;
  const __bf16* Vg = VT + ((size_t)(b * HH + h) * DHD) * SS;
  const __bf16* Kg0 = Kg + (size_t)r0i * DD + s0i * 8;
  const __bf16* Kg1 = Kg + (size_t)r1i * DD + s1i * 8;
  const __bf16* Vg0 = Vg + (size_t)r0i * SS + s0i * 8;
  const __bf16* Vg1 = Vg + (size_t)r1i * SS + s1i * 8;

  // prologue: stage kb=0 into buf 0
  gload_lds16(Kg0, (char*)Ks[0] + lb0);
  gload_lds16(Kg1, (char*)Ks[0] + lb1);
  gload_lds16(Vg0, (char*)Vs[0] + lb0);
  gload_lds16(Vg1, (char*)Vs[0] + lb1);

  float m_run[2][4], l_run[2][4];
  f32x4 ctx[2][4];
#pragma unroll
  for (int m = 0; m < 2; ++m)
#pragma unroll
    for (int r = 0; r < 4; ++r) {
      m_run[m][r] = -1e30f;
      l_run[m][r] = 0.f;
      ctx[m][r] = (f32x4){0.f, 0.f, 0.f, 0.f};
    }
  const float scale = 0.03125f;  // 1/sqrt(1024)
  __syncthreads();

  const int NT = SS / 64;
  for (int it = 0; it < NT; ++it) {
    int cur = it & 1;
    int kb = it * 64;
    if (it + 1 < NT) {
      size_t ko = (size_t)(it + 1) * 64 * DD;
      int vo = (it + 1) * 64;
      gload_lds16(Kg0 + ko, (char*)Ks[cur ^ 1] + lb0);
      gload_lds16(Kg1 + ko, (char*)Ks[cur ^ 1] + lb1);
      gload_lds16(Vg0 + vo, (char*)Vs[cur ^ 1] + lb0);
      gload_lds16(Vg1 + vo, (char*)Vs[cur ^ 1] + lb1);
    }
    // ---- QK^T: s[m][f] = Q[32 rows] . K[64 keys]^T
    const char* Kb = (const char*)Ks[cur];
    f32x4 s[2][4];
#pragma unroll
    for (int m = 0; m < 2; ++m)
#pragma unroll
      for (int f = 0; f < 4; ++f) s[m][f] = (f32x4){0.f, 0.f, 0.f, 0.f};
#pragma unroll
    for (int f = 0; f < 4; ++f) {
      int row = f * 16 + lr;
#pragma unroll
      for (int kc = 0; kc < 2; ++kc) {
        bf16x8 kf = *(const bf16x8*)(Kb + row * 128 + (((kc * 4 + lg) ^ (row & 7)) << 4));
#pragma unroll
        for (int m = 0; m < 2; ++m) s[m][f] = mfma16(qa[m][kc], kf, s[m][f]);
      }
    }
    // ---- softmax; per-lane rows: q = m*16 + 4*lg + r, key = kb + 16f + lr
    float mk[4];
#pragma unroll
    for (int f = 0; f < 4; ++f) mk[f] = maskS[kb + f * 16 + lr];
    float sv[2][4][4];
#pragma unroll
    for (int m = 0; m < 2; ++m) {
      float rmax[4];
#pragma unroll
      for (int r = 0; r < 4; ++r) {
#pragma unroll
        for (int f = 0; f < 4; ++f) sv[m][f][r] = s[m][f][r] * scale + mk[f];
        rmax[r] = fmaxf(fmaxf(sv[m][0][r], sv[m][1][r]), fmaxf(sv[m][2][r], sv[m][3][r]));
      }
#pragma unroll
      for (int off = 1; off < 16; off <<= 1)
#pragma unroll
        for (int r = 0; r < 4; ++r) rmax[r] = fmaxf(rmax[r], __shfl_xor(rmax[r], off, 64));
      float alpha[4], rsum[4];
#pragma unroll
      for (int r = 0; r < 4; ++r) {
        float mnew = fmaxf(m_run[m][r], rmax[r]);
        alpha[r] = __expf(m_run[m][r] - mnew);
        m_run[m][r] = mnew;
        float p0 = __expf(sv[m][0][r] - mnew);
        float p1 = __expf(sv[m][1][r] - mnew);
        float p2 = __expf(sv[m][2][r] - mnew);
        float p3 = __expf(sv[m][3][r] - mnew);
        sv[m][0][r] = p0; sv[m][1][r] = p1; sv[m][2][r] = p2; sv[m][3][r] = p3;
        rsum[r] = (p0 + p1) + (p2 + p3);
      }
#pragma unroll
      for (int off = 1; off < 16; off <<= 1)
#pragma unroll
        for (int r = 0; r < 4; ++r) rsum[r] += __shfl_xor(rsum[r], off, 64);
#pragma unroll
      for (int r = 0; r < 4; ++r) {
        l_run[m][r] = l_run[m][r] * alpha[r] + rsum[r];
#pragma unroll
        for (int c = 0; c < 4; ++c) ctx[m][c][r] *= alpha[r];
      }
      // P -> wave-private LDS
#pragma unroll
      for (int f = 0; f < 4; ++f)
#pragma unroll
        for (int r = 0; r < 4; ++r)
          pS[wave][m * 16 + 4 * lg + r][f * 16 + lr] = (__bf16)sv[m][f][r];
    }
    // re-read P as PV A-fragments
    bf16x8 pa[2][2];
#pragma unroll
    for (int m = 0; m < 2; ++m)
#pragma unroll
      for (int kc = 0; kc < 2; ++kc)
        pa[m][kc] = *(const bf16x8*)(&pS[wave][m * 16 + lr][kc * 32 + 8 * lg]);
    // ---- PV: ctx[m][c] += P[32x64] @ V[64 keys][16c..16c+15]
    const char* Vb = (const char*)Vs[cur];
#pragma unroll
    for (int c = 0; c < 4; ++c) {
      int row = c * 16 + lr;
#pragma unroll
      for (int kc = 0; kc < 2; ++kc) {
        bf16x8 vf = *(const bf16x8*)(Vb + row * 128 + (((kc * 4 + lg) ^ (row & 7)) << 4));
#pragma unroll
        for (int m = 0; m < 2; ++m) ctx[m][c] = mfma16(pa[m][kc], vf, ctx[m][c]);
      }
    }
    __syncthreads();
  }
  // ---- epilogue
#pragma unroll
  for (int m = 0; m < 2; ++m) {
    __bf16* op = ctxb + ((size_t)(b * SS) + q0 + m * 16 + 4 * lg) * DD + h * DHD + lr;
#pragma unroll
    for (int r = 0; r < 4; ++r) {
      float inv = 1.0f / l_run[m][r];
#pragma unroll
      for (int c = 0; c < 4; ++c)
        op[(size_t)r * DD + c * 16] = (__bf16)(ctx[m][c][r] * inv);
    }
  }
}

// ---------------------------------------------------------------- launcher
extern "C" void kernel_launch(void* const* d_in, const int* in_sizes, int n_in,
                              void* d_out, int out_size, void* d_ws, size_t ws_size,
                              hipStream_t stream) {
  const float* x    = (const float*)d_in[0];
  const float* mask = (const float*)d_in[1];
  const float* Wq   = (const float*)d_in[2];
  const float* Wk   = (const float*)d_in[3];
  const float* Wv   = (const float*)d_in[4];
  const float* Wo   = (const float*)d_in[5];
  const float* bo   = (const float*)d_in[6];
  float* out = (float*)d_out;

  char* ws = (char*)d_ws;
  const size_t MB = 1024 * 1024;
  __bf16* xb   = (__bf16*)(ws + 0);        // 8 MB (reused as ctxb later)
  __bf16* WqT  = (__bf16*)(ws + 8 * MB);   // 2 MB
  __bf16* WkT  = (__bf16*)(ws + 10 * MB);  // 2 MB
  __bf16* WvT  = (__bf16*)(ws + 12 * MB);  // 2 MB
  __bf16* WoT  = (__bf16*)(ws + 14 * MB);  // 2 MB
  __bf16* qb   = (__bf16*)(ws + 16 * MB);  // 8 MB
  __bf16* kbuf = (__bf16*)(ws + 24 * MB);  // 8 MB
  __bf16* vb   = (__bf16*)(ws + 32 * MB);  // 8 MB
  __bf16* vtb  = (__bf16*)(ws + 40 * MB);  // 8 MB
  __bf16* ctxb = xb;

  const int M = BB * SS;  // 4096
  cast_x_kernel<<<(M * DD) / 1024, 256, 0, stream>>>(x, xb, (M * DD) / 4);
  dim3 gw(DD / 64, DD / 64);
  wtrans_kernel<<<gw, 256, 0, stream>>>(Wq, WqT);
  wtrans_kernel<<<gw, 256, 0, stream>>>(Wk, WkT);
  wtrans_kernel<<<gw, 256, 0, stream>>>(Wv, WvT);
  wtrans_kernel<<<gw, 256, 0, stream>>>(Wo, WoT);
  dim3 gg(M / 128, DD / 128);
  gemm128_kernel<false><<<gg, 256, 0, stream>>>(xb, WqT, nullptr, qb, nullptr, M, DD, DD);
  gemm128_kernel<false><<<gg, 256, 0, stream>>>(xb, WkT, nullptr, kbuf, nullptr, M, DD, DD);
  gemm128_kernel<false><<<gg, 256, 0, stream>>>(xb, WvT, nullptr, vb, nullptr, M, DD, DD);
  dim3 gt(SS / 64, HH, BB);
  vtrans_kernel<<<gt, 256, 0, stream>>>(vb, vtb);
  dim3 ga(SS / 128, HH, BB);
  attn_kernel<<<ga, 256, 0, stream>>>(qb, kbuf, vtb, mask, ctxb);
  gemm128_kernel<true><<<gg, 256, 0, stream>>>(ctxb, WoT, out, nullptr, bo, M, DD, DD);
}

// Round 7
// 229.782 us; speedup vs baseline: 2.4563x; 1.2982x over previous
//
#include <hip/hip_runtime.h>
#include <hip/hip_bf16.h>

// Problem constants
#define BB 2
#define SS 2048
#define DD 1024
#define HH 16
#define DHD 64
#define QKLD 2048  // row stride of fused QK buffer

typedef __attribute__((ext_vector_type(8))) __bf16 bf16x8;
typedef __attribute__((ext_vector_type(4))) __bf16 bf16x4;
typedef __attribute__((ext_vector_type(4))) float f32x4;

__device__ __forceinline__ f32x4 mfma16(bf16x8 a, bf16x8 b, f32x4 c) {
  return __builtin_amdgcn_mfma_f32_16x16x32_bf16(a, b, c, 0, 0, 0);
}
__device__ __forceinline__ void gload_lds16(const void* g, void* l) {
  __builtin_amdgcn_global_load_lds((__attribute__((address_space(1))) const void*)g,
                                   (__attribute__((address_space(3))) void*)l, 16, 0, 0);
}

// --------------------------------- cast x -> bf16, plus em = exp(mask) -> bf16
__global__ __launch_bounds__(256) void cast_x_em_kernel(
    const float* __restrict__ in, __bf16* __restrict__ out,
    const float* __restrict__ mask, __bf16* __restrict__ embf, int n4) {
  int i = blockIdx.x * 256 + threadIdx.x;
  if (i < n4) {
    float4 f = ((const float4*)in)[i];
    bf16x4 o;
    o[0] = (__bf16)f.x; o[1] = (__bf16)f.y; o[2] = (__bf16)f.z; o[3] = (__bf16)f.w;
    *(bf16x4*)(out + (size_t)i * 4) = o;
  } else {
    int j = i - n4;
    if (j < BB * SS) embf[j] = (__bf16)__expf(mask[j]);
  }
}

// ------------------- all four W [K,N] fp32 -> WT [N,K] bf16 (z selects weight)
__global__ __launch_bounds__(256) void wtrans4_kernel(
    const float* __restrict__ Wq, const float* __restrict__ Wk,
    const float* __restrict__ Wv, const float* __restrict__ Wo,
    __bf16* __restrict__ WTbase) {
  int z = blockIdx.z;
  const float* W = (z == 0) ? Wq : (z == 1) ? Wk : (z == 2) ? Wv : Wo;
  __bf16* WT = WTbase + ((size_t)z << 20);
  __shared__ __bf16 t[64][65];
  int c0 = blockIdx.x * 64, r0 = blockIdx.y * 64;
  int tid = threadIdx.x;
  {
    int rr = tid >> 4, cg = tid & 15;
#pragma unroll
    for (int it = 0; it < 4; ++it) {
      int r = rr + it * 16;
      float4 f = *(const float4*)(W + (size_t)(r0 + r) * DD + c0 + cg * 4);
      t[r][cg * 4 + 0] = (__bf16)f.x;
      t[r][cg * 4 + 1] = (__bf16)f.y;
      t[r][cg * 4 + 2] = (__bf16)f.z;
      t[r][cg * 4 + 3] = (__bf16)f.w;
    }
  }
  __syncthreads();
  {
    int sg = tid & 7;
#pragma unroll
    for (int it = 0; it < 2; ++it) {
      int wc = (tid >> 3) + it * 32;
      __bf16 tmp[8];
#pragma unroll
      for (int e = 0; e < 8; ++e) tmp[e] = t[sg * 8 + e][wc];
      bf16x8 o;
#pragma unroll
      for (int e = 0; e < 8; ++e) o[e] = tmp[e];
      *(bf16x8*)(WT + (size_t)(c0 + wc) * DD + r0 + sg * 8) = o;
    }
  }
}

// ---------------------------------------------------------------- GEMM (m97-style)
// C[M,N] = A[M,K] @ BT[N,K]^T. 128x128 tile, BK=32, 4 waves x (64x64).
// MODE 0: bf16 C. MODE 1: f32 C + bias. MODE 2: write C'[dh][s]*em[s] into
//         vt[b,h,d,s] (transposed V-projection with folded exp(mask)).
template <int MODE>
__global__ __launch_bounds__(256, 2) void gemm128_kernel(
    const __bf16* __restrict__ A, const __bf16* __restrict__ BT,
    float* __restrict__ Cf, __bf16* __restrict__ Cb,
    const float* __restrict__ bias, const __bf16* __restrict__ embf,
    int M, int N, int K) {
  __shared__ __bf16 As[2][128 * 32];
  __shared__ __bf16 Bs[2][128 * 32];
  int tid = threadIdx.x;
  int lane = tid & 63, wave = tid >> 6;
  int lr = lane & 15, lg = lane >> 4;
  int wr = wave >> 1, wc = wave & 1;
  int m0 = blockIdx.x * 128, n0 = blockIdx.y * 128;

  int o0 = wave * 1024 + lane * 16;
  int r0i = o0 >> 6, s0i = ((o0 >> 4) & 3) ^ (r0i & 3);
  int o1 = o0 + 4096;
  int r1i = o1 >> 6, s1i = ((o1 >> 4) & 3) ^ (r1i & 3);

  const __bf16* Ag0 = A + (size_t)(m0 + r0i) * K + s0i * 8;
  const __bf16* Ag1 = A + (size_t)(m0 + r1i) * K + s1i * 8;
  const __bf16* Bg0 = BT + (size_t)(n0 + r0i) * K + s0i * 8;
  const __bf16* Bg1 = BT + (size_t)(n0 + r1i) * K + s1i * 8;
  int lb0 = wave * 1024, lb1 = wave * 1024 + 4096;

  f32x4 acc[4][4];
#pragma unroll
  for (int m = 0; m < 4; ++m)
#pragma unroll
    for (int n = 0; n < 4; ++n) acc[m][n] = (f32x4){0.f, 0.f, 0.f, 0.f};

  gload_lds16(Ag0, (char*)As[0] + lb0);
  gload_lds16(Ag1, (char*)As[0] + lb1);
  gload_lds16(Bg0, (char*)Bs[0] + lb0);
  gload_lds16(Bg1, (char*)Bs[0] + lb1);
  __syncthreads();

  int NK = K >> 5;
  for (int it = 0; it < NK; ++it) {
    int cur = it & 1;
    if (it + 1 < NK) {
      int ko = (it + 1) * 32;
      gload_lds16(Ag0 + ko, (char*)As[cur ^ 1] + lb0);
      gload_lds16(Ag1 + ko, (char*)As[cur ^ 1] + lb1);
      gload_lds16(Bg0 + ko, (char*)Bs[cur ^ 1] + lb0);
      gload_lds16(Bg1 + ko, (char*)Bs[cur ^ 1] + lb1);
    }
    const char* Ab = (const char*)As[cur];
    const char* Bb = (const char*)Bs[cur];
    bf16x8 af[4], bfr[4];
#pragma unroll
    for (int m = 0; m < 4; ++m) {
      int row = wr * 64 + m * 16 + lr;
      af[m] = *(const bf16x8*)(Ab + row * 64 + ((lg ^ (row & 3)) << 4));
    }
#pragma unroll
    for (int n = 0; n < 4; ++n) {
      int row = wc * 64 + n * 16 + lr;
      bfr[n] = *(const bf16x8*)(Bb + row * 64 + ((lg ^ (row & 3)) << 4));
    }
#pragma unroll
    for (int m = 0; m < 4; ++m)
#pragma unroll
      for (int n = 0; n < 4; ++n) acc[m][n] = mfma16(af[m], bfr[n], acc[m][n]);
    __syncthreads();
  }

  // epilogue: D layout col = lane&15, row = 4*(lane>>4)+reg
#pragma unroll
  for (int m = 0; m < 4; ++m) {
#pragma unroll
    for (int n = 0; n < 4; ++n) {
      int cc = n0 + wc * 64 + n * 16 + lr;
      float ef = 0.f;
      if constexpr (MODE == 2) ef = (float)embf[cc];
#pragma unroll
      for (int r = 0; r < 4; ++r) {
        int rr = m0 + wr * 64 + m * 16 + 4 * lg + r;
        if constexpr (MODE == 1) {
          Cf[(size_t)rr * N + cc] = acc[m][n][r] + bias[cc];
        } else if constexpr (MODE == 0) {
          Cb[(size_t)rr * N + cc] = (__bf16)acc[m][n][r];
        } else {
          // rr = dh (0..1023), cc = s-global (0..4095)
          int bb2 = cc >> 11, sl = cc & (SS - 1);
          int hh = rr >> 6, dd2 = rr & 63;
          Cb[(((size_t)bb2 * HH + hh) * DHD + dd2) * SS + sl] =
              (__bf16)(acc[m][n][r] * ef);
        }
      }
    }
  }
}

// ---------------------------------------------------------------- attention
// grid (S/128, H, B), 4 waves x 32 q-rows, 16x16x32 MFMA path (R2-verified
// fragments). Static softmax: p = exp(s*scale); mask folded as em=exp(mask)
// into V' (numerator) and an em-broadcast MFMA (denominator). No max tracking,
// no shfl reductions, no rescale. P roundtrips via wave-private LDS (R2 path).
__global__ __launch_bounds__(256, 2) void attn_kernel(
    const __bf16* __restrict__ QK, const __bf16* __restrict__ VT,
    const __bf16* __restrict__ embf, __bf16* __restrict__ ctxb) {
  __shared__ __bf16 Ks[2][64 * 64];
  __shared__ __bf16 Vs[2][64 * 64];
  __shared__ __attribute__((aligned(16))) __bf16 pS[4][32][72];

  int h = blockIdx.y, b = blockIdx.z;
  int tid = threadIdx.x;
  int wave = tid >> 6, lane = tid & 63;
  int lr = lane & 15, lg = lane >> 4;

  int q0 = blockIdx.x * 128 + wave * 32;
  const __bf16* qp = QK + ((size_t)(b * SS) + q0 + lr) * QKLD + h * DHD;
  bf16x8 qa[2][2];
#pragma unroll
  for (int m = 0; m < 2; ++m)
#pragma unroll
    for (int kc = 0; kc < 2; ++kc)
      qa[m][kc] = *(const bf16x8*)(qp + (size_t)m * 16 * QKLD + kc * 32 + 8 * lg);

  // staging geometry: 64x64 bf16 tile (128B rows), 2 issues/thread,
  // linear LDS dest + inverse-swizzled global source (rule #21)
  int o0 = tid * 16;
  int row0 = o0 >> 7;                      // 0..31
  int ss0 = ((o0 >> 4) & 7) ^ (row0 & 7);  // source slot
  int lw0 = wave * 1024, lw1 = wave * 1024 + 4096;

  const __bf16* kg = QK + (size_t)(b * SS) * QKLD + DD + h * DHD;  // K at +DD
  const __bf16* vg = VT + ((size_t)(b * HH + h) * DHD) * SS;
  const __bf16* Kg0 = kg + (size_t)row0 * QKLD + ss0 * 8;
  const __bf16* Kg1 = kg + (size_t)(row0 + 32) * QKLD + ss0 * 8;
  const __bf16* Vg0 = vg + (size_t)row0 * SS + ss0 * 8;
  const __bf16* Vg1 = vg + (size_t)(row0 + 32) * SS + ss0 * 8;
  const __bf16* ep = embf + b * SS + 8 * lg;

  // prologue: stage tile 0
  gload_lds16(Kg0, (char*)Ks[0] + lw0);
  gload_lds16(Kg1, (char*)Ks[0] + lw1);
  gload_lds16(Vg0, (char*)Vs[0] + lw0);
  gload_lds16(Vg1, (char*)Vs[0] + lw1);

  f32x4 ctx[2][4], lacc[2];
#pragma unroll
  for (int m = 0; m < 2; ++m) {
    lacc[m] = (f32x4){0.f, 0.f, 0.f, 0.f};
#pragma unroll
    for (int c = 0; c < 4; ++c) ctx[m][c] = (f32x4){0.f, 0.f, 0.f, 0.f};
  }
  const float SCALE = 0.03125f;  // 1/sqrt(1024)
  __syncthreads();

  const int NT = SS / 64;
  for (int it = 0; it < NT; ++it) {
    int cur = it & 1;
    int kb = it * 64;
    if (it + 1 < NT) {
      size_t ko = (size_t)(it + 1) * 64 * QKLD;
      int vo = (it + 1) * 64;
      gload_lds16(Kg0 + ko, (char*)Ks[cur ^ 1] + lw0);
      gload_lds16(Kg1 + ko, (char*)Ks[cur ^ 1] + lw1);
      gload_lds16(Vg0 + vo, (char*)Vs[cur ^ 1] + lw0);
      gload_lds16(Vg1 + vo, (char*)Vs[cur ^ 1] + lw1);
    }
    const char* Kb = (const char*)Ks[cur];
    const char* Vb = (const char*)Vs[cur];
    // ---- QK^T: s[m][f], D col = key (f*16+lr), row = q (m*16+4*lg+r)
    f32x4 s[2][4];
#pragma unroll
    for (int m = 0; m < 2; ++m)
#pragma unroll
      for (int f = 0; f < 4; ++f) s[m][f] = (f32x4){0.f, 0.f, 0.f, 0.f};
#pragma unroll
    for (int f = 0; f < 4; ++f) {
      int row = f * 16 + lr;
#pragma unroll
      for (int kc = 0; kc < 2; ++kc) {
        bf16x8 kf = *(const bf16x8*)(Kb + row * 128 + (((kc * 4 + lg) ^ (row & 7)) << 4));
#pragma unroll
        for (int m = 0; m < 2; ++m) s[m][f] = mfma16(qa[m][kc], kf, s[m][f]);
      }
    }
    // ---- static softmax: p = exp(s*scale), no max, no mask-add -> pS
#pragma unroll
    for (int m = 0; m < 2; ++m)
#pragma unroll
      for (int f = 0; f < 4; ++f)
#pragma unroll
        for (int r = 0; r < 4; ++r)
          pS[wave][m * 16 + 4 * lg + r][f * 16 + lr] =
              (__bf16)__expf(s[m][f][r] * SCALE);
    // em B-frags for this tile: k = 8*lg + e -> em[kb + kc*32 + 8*lg + e]
    bf16x8 emf[2];
    emf[0] = *(const bf16x8*)(ep + kb);
    emf[1] = *(const bf16x8*)(ep + kb + 32);
    // ---- re-read P as PV A-frags (wave-private, same-wave LDS ordering)
    bf16x8 pa[2][2];
#pragma unroll
    for (int m = 0; m < 2; ++m)
#pragma unroll
      for (int kc = 0; kc < 2; ++kc)
        pa[m][kc] = *(const bf16x8*)(&pS[wave][m * 16 + lr][kc * 32 + 8 * lg]);
    // ---- denominator via em-broadcast MFMA: lacc[q] += sum_key p*em
#pragma unroll
    for (int m = 0; m < 2; ++m) {
      lacc[m] = mfma16(pa[m][0], emf[0], lacc[m]);
      lacc[m] = mfma16(pa[m][1], emf[1], lacc[m]);
    }
    // ---- PV: ctx[m][c] += P[32x64] @ V'[64 keys][16c..16c+15]
#pragma unroll
    for (int c = 0; c < 4; ++c) {
      int row = c * 16 + lr;
#pragma unroll
      for (int kc = 0; kc < 2; ++kc) {
        bf16x8 vf = *(const bf16x8*)(Vb + row * 128 + (((kc * 4 + lg) ^ (row & 7)) << 4));
#pragma unroll
        for (int m = 0; m < 2; ++m) ctx[m][c] = mfma16(pa[m][kc], vf, ctx[m][c]);
      }
    }
    __syncthreads();
  }
  // ---- epilogue: divide by denominator, store bf16
#pragma unroll
  for (int m = 0; m < 2; ++m) {
    __bf16* op = ctxb + ((size_t)(b * SS) + q0 + m * 16 + 4 * lg) * DD + h * DHD + lr;
#pragma unroll
    for (int r = 0; r < 4; ++r) {
      float inv = 1.0f / lacc[m][r];
#pragma unroll
      for (int c = 0; c < 4; ++c)
        op[(size_t)r * DD + c * 16] = (__bf16)(ctx[m][c][r] * inv);
    }
  }
}

// ---------------------------------------------------------------- launcher
extern "C" void kernel_launch(void* const* d_in, const int* in_sizes, int n_in,
                              void* d_out, int out_size, void* d_ws, size_t ws_size,
                              hipStream_t stream) {
  const float* x    = (const float*)d_in[0];
  const float* mask = (const float*)d_in[1];
  const float* Wq   = (const float*)d_in[2];
  const float* Wk   = (const float*)d_in[3];
  const float* Wv   = (const float*)d_in[4];
  const float* Wo   = (const float*)d_in[5];
  const float* bo   = (const float*)d_in[6];
  float* out = (float*)d_out;

  char* ws = (char*)d_ws;
  const size_t MB = 1024 * 1024;
  __bf16* xb   = (__bf16*)(ws + 0);        // 8 MB (reused as ctxb)
  __bf16* WqT  = (__bf16*)(ws + 8 * MB);   // 2 MB (WkT/WvT/WoT contiguous after)
  __bf16* WvT  = (__bf16*)(ws + 12 * MB);
  __bf16* WoT  = (__bf16*)(ws + 14 * MB);
  __bf16* qkb  = (__bf16*)(ws + 16 * MB);  // 16 MB: [4096][2048] fused Q|K
  __bf16* vtb  = (__bf16*)(ws + 32 * MB);  // 8 MB: V'[b,h,d,s] (em-folded)
  __bf16* embf = (__bf16*)(ws + 40 * MB);  // 8 KB
  __bf16* ctxb = xb;

  const int M = BB * SS;  // 4096
  const int n4 = M * DD / 4;
  cast_x_em_kernel<<<n4 / 256 + 16, 256, 0, stream>>>(x, xb, mask, embf, n4);
  wtrans4_kernel<<<dim3(16, 16, 4), 256, 0, stream>>>(Wq, Wk, Wv, Wo, WqT);
  // fused Q|K projection: BT = [WqT; WkT] (contiguous), N = 2048
  gemm128_kernel<0><<<dim3(32, 16), 256, 0, stream>>>(
      xb, WqT, nullptr, qkb, nullptr, nullptr, M, 2048, DD);
  // transposed V projection with em folding: C'[dh][s] -> vt[b,h,d,s]*em
  gemm128_kernel<2><<<dim3(8, 32), 256, 0, stream>>>(
      WvT, xb, nullptr, vtb, nullptr, embf, DD, M, DD);
  attn_kernel<<<dim3(16, 16, 2), 256, 0, stream>>>(qkb, vtb, embf, ctxb);
  gemm128_kernel<1><<<dim3(32, 8), 256, 0, stream>>>(
      ctxb, WoT, out, nullptr, bo, nullptr, M, DD, DD);
}

// Round 8
// 212.919 us; speedup vs baseline: 2.6508x; 1.0792x over previous
//
#include <hip/hip_runtime.h>
#include <hip/hip_bf16.h>

// Problem constants
#define BB 2
#define SS 2048
#define DD 1024
#define HH 16
#define DHD 64
#define QKLD 2048  // row stride of fused QK buffer

typedef __attribute__((ext_vector_type(8))) __bf16 bf16x8;
typedef __attribute__((ext_vector_type(4))) __bf16 bf16x4;
typedef __attribute__((ext_vector_type(4))) float f32x4;

__device__ __forceinline__ f32x4 mfma16(bf16x8 a, bf16x8 b, f32x4 c) {
  return __builtin_amdgcn_mfma_f32_16x16x32_bf16(a, b, c, 0, 0, 0);
}
__device__ __forceinline__ void gload_lds16(const void* g, void* l) {
  __builtin_amdgcn_global_load_lds((__attribute__((address_space(1))) const void*)g,
                                   (__attribute__((address_space(3))) void*)l, 16, 0, 0);
}

// ---------------------------------------------------------------- prep kernel
// One launch: cast x -> bf16 (blocks 0..4095), em = exp(mask) (4096..4111),
// all four W [K,N] fp32 -> WT [N,K] bf16 (4112..5135).
__global__ __launch_bounds__(256) void prep_kernel(
    const float* __restrict__ x, __bf16* __restrict__ xb,
    const float* __restrict__ mask, __bf16* __restrict__ embf,
    const float* __restrict__ Wq, const float* __restrict__ Wk,
    const float* __restrict__ Wv, const float* __restrict__ Wo,
    __bf16* __restrict__ WTbase) {
  __shared__ __bf16 t[64][65];
  int id = blockIdx.x, tid = threadIdx.x;
  if (id < 4096) {
    int i = id * 256 + tid;  // n4 = 4096*1024/4 = 1048576 > max i ✓
    float4 f = ((const float4*)x)[i];
    bf16x4 o;
    o[0] = (__bf16)f.x; o[1] = (__bf16)f.y; o[2] = (__bf16)f.z; o[3] = (__bf16)f.w;
    *(bf16x4*)(xb + (size_t)i * 4) = o;
    return;
  }
  if (id < 4112) {
    int j = (id - 4096) * 256 + tid;  // < BB*SS = 4096 ✓
    embf[j] = (__bf16)__expf(mask[j]);
    return;
  }
  int idx = id - 4112;
  int z = idx >> 8, rem = idx & 255;
  const float* W = (z == 0) ? Wq : (z == 1) ? Wk : (z == 2) ? Wv : Wo;
  __bf16* WT = WTbase + ((size_t)z << 20);
  int c0 = (rem & 15) * 64, r0 = (rem >> 4) * 64;
  {
    int rr = tid >> 4, cg = tid & 15;
#pragma unroll
    for (int it = 0; it < 4; ++it) {
      int r = rr + it * 16;
      float4 f = *(const float4*)(W + (size_t)(r0 + r) * DD + c0 + cg * 4);
      t[r][cg * 4 + 0] = (__bf16)f.x;
      t[r][cg * 4 + 1] = (__bf16)f.y;
      t[r][cg * 4 + 2] = (__bf16)f.z;
      t[r][cg * 4 + 3] = (__bf16)f.w;
    }
  }
  __syncthreads();
  {
    int sg = tid & 7;
#pragma unroll
    for (int it = 0; it < 2; ++it) {
      int wc = (tid >> 3) + it * 32;
      __bf16 tmp[8];
#pragma unroll
      for (int e = 0; e < 8; ++e) tmp[e] = t[sg * 8 + e][wc];
      bf16x8 o;
#pragma unroll
      for (int e = 0; e < 8; ++e) o[e] = tmp[e];
      *(bf16x8*)(WT + (size_t)(c0 + wc) * DD + r0 + sg * 8) = o;
    }
  }
}

// ---------------------------------------------------------------- GEMM body
// C[M,N] = A[M,K] @ BT[N,K]^T. 128x128 tile, BK=32, 4 waves x (64x64).
// MODE 0: bf16 C. MODE 1: f32 C + bias. MODE 2: write C'[dh][s]*em[s] into
//         vt[b,h,d,s] (transposed V-projection with folded exp(mask)).
// As/Bs: 2 buffers of 8192 bytes each (caller-allocated LDS).
template <int MODE>
__device__ __forceinline__ void gemm_body(
    char* AsB, char* BsB, int bx, int by,
    const __bf16* __restrict__ A, const __bf16* __restrict__ BT,
    float* __restrict__ Cf, __bf16* __restrict__ Cb,
    const float* __restrict__ bias, const __bf16* __restrict__ embf,
    int M, int N, int K) {
  int tid = threadIdx.x;
  int lane = tid & 63, wave = tid >> 6;
  int lr = lane & 15, lg = lane >> 4;
  int wr = wave >> 1, wc = wave & 1;
  int m0 = bx * 128, n0 = by * 128;

  int o0 = wave * 1024 + lane * 16;
  int r0i = o0 >> 6, s0i = ((o0 >> 4) & 3) ^ (r0i & 3);
  int o1 = o0 + 4096;
  int r1i = o1 >> 6, s1i = ((o1 >> 4) & 3) ^ (r1i & 3);

  const __bf16* Ag0 = A + (size_t)(m0 + r0i) * K + s0i * 8;
  const __bf16* Ag1 = A + (size_t)(m0 + r1i) * K + s1i * 8;
  const __bf16* Bg0 = BT + (size_t)(n0 + r0i) * K + s0i * 8;
  const __bf16* Bg1 = BT + (size_t)(n0 + r1i) * K + s1i * 8;
  int lb0 = wave * 1024, lb1 = wave * 1024 + 4096;

  f32x4 acc[4][4];
#pragma unroll
  for (int m = 0; m < 4; ++m)
#pragma unroll
    for (int n = 0; n < 4; ++n) acc[m][n] = (f32x4){0.f, 0.f, 0.f, 0.f};

  gload_lds16(Ag0, AsB + lb0);
  gload_lds16(Ag1, AsB + lb1);
  gload_lds16(Bg0, BsB + lb0);
  gload_lds16(Bg1, BsB + lb1);
  __syncthreads();

  int NK = K >> 5;
  for (int it = 0; it < NK; ++it) {
    int cur = it & 1;
    if (it + 1 < NK) {
      int ko = (it + 1) * 32;
      char* An = AsB + (cur ^ 1) * 8192;
      char* Bn = BsB + (cur ^ 1) * 8192;
      gload_lds16(Ag0 + ko, An + lb0);
      gload_lds16(Ag1 + ko, An + lb1);
      gload_lds16(Bg0 + ko, Bn + lb0);
      gload_lds16(Bg1 + ko, Bn + lb1);
    }
    const char* Ab = AsB + cur * 8192;
    const char* Bb = BsB + cur * 8192;
    bf16x8 af[4], bfr[4];
#pragma unroll
    for (int m = 0; m < 4; ++m) {
      int row = wr * 64 + m * 16 + lr;
      af[m] = *(const bf16x8*)(Ab + row * 64 + ((lg ^ (row & 3)) << 4));
    }
#pragma unroll
    for (int n = 0; n < 4; ++n) {
      int row = wc * 64 + n * 16 + lr;
      bfr[n] = *(const bf16x8*)(Bb + row * 64 + ((lg ^ (row & 3)) << 4));
    }
#pragma unroll
    for (int m = 0; m < 4; ++m)
#pragma unroll
      for (int n = 0; n < 4; ++n) acc[m][n] = mfma16(af[m], bfr[n], acc[m][n]);
    __syncthreads();
  }

  // epilogue: D layout col = lane&15, row = 4*(lane>>4)+reg
#pragma unroll
  for (int m = 0; m < 4; ++m) {
#pragma unroll
    for (int n = 0; n < 4; ++n) {
      int cc = n0 + wc * 64 + n * 16 + lr;
      float ef = 0.f;
      if constexpr (MODE == 2) ef = (float)embf[cc];
#pragma unroll
      for (int r = 0; r < 4; ++r) {
        int rr = m0 + wr * 64 + m * 16 + 4 * lg + r;
        if constexpr (MODE == 1) {
          Cf[(size_t)rr * N + cc] = acc[m][n][r] + bias[cc];
        } else if constexpr (MODE == 0) {
          Cb[(size_t)rr * N + cc] = (__bf16)acc[m][n][r];
        } else {
          // rr = dh (0..1023), cc = s-global (0..4095)
          int bb2 = cc >> 11, sl = cc & (SS - 1);
          int hh = rr >> 6, dd2 = rr & 63;
          Cb[(((size_t)bb2 * HH + hh) * DHD + dd2) * SS + sl] =
              (__bf16)(acc[m][n][r] * ef);
        }
      }
    }
  }
}

// ------------- one launch: QK projection (blocks 0..511) + V' (512..767)
__global__ __launch_bounds__(256, 2) void proj_kernel(
    const __bf16* __restrict__ xb, const __bf16* __restrict__ WqT,
    const __bf16* __restrict__ WvT, __bf16* __restrict__ qkb,
    __bf16* __restrict__ vtb, const __bf16* __restrict__ embf) {
  __shared__ __bf16 As[2][128 * 32];
  __shared__ __bf16 Bs[2][128 * 32];
  int id = blockIdx.x;
  if (id < 512) {
    gemm_body<0>((char*)As, (char*)Bs, id & 31, id >> 5,
                 xb, WqT, nullptr, qkb, nullptr, nullptr, 4096, 2048, 1024);
  } else {
    int i2 = id - 512;
    gemm_body<2>((char*)As, (char*)Bs, i2 & 7, i2 >> 3,
                 WvT, xb, nullptr, vtb, nullptr, embf, 1024, 4096, 1024);
  }
}

// ------------- output projection (f32 + bias)
__global__ __launch_bounds__(256, 2) void ogemm_kernel(
    const __bf16* __restrict__ ctxb, const __bf16* __restrict__ WoT,
    float* __restrict__ out, const float* __restrict__ bo) {
  __shared__ __bf16 As[2][128 * 32];
  __shared__ __bf16 Bs[2][128 * 32];
  gemm_body<1>((char*)As, (char*)Bs, blockIdx.x, blockIdx.y,
               ctxb, WoT, out, nullptr, bo, nullptr, 4096, 1024, 1024);
}

// ---------------------------------------------------------------- attention
// grid (S/128, H, B), 8 waves x 16 q-rows (512 threads), 16x16x32 MFMA path.
// Static softmax: p = exp(s*scale); mask folded as em=exp(mask) into V'
// (numerator) and an em-broadcast MFMA (denominator). Per-wave fragment math
// identical to the R7-verified kernel; only the wave count changed (TLP).
__global__ __launch_bounds__(512, 4) void attn_kernel(
    const __bf16* __restrict__ QK, const __bf16* __restrict__ VT,
    const __bf16* __restrict__ embf, __bf16* __restrict__ ctxb) {
  __shared__ __bf16 Ks[2][64 * 64];
  __shared__ __bf16 Vs[2][64 * 64];
  __shared__ __attribute__((aligned(16))) __bf16 pS[8][16][72];

  int h = blockIdx.y, b = blockIdx.z;
  int tid = threadIdx.x;
  int wave = tid >> 6, lane = tid & 63;
  int lr = lane & 15, lg = lane >> 4;

  int q0 = blockIdx.x * 128 + wave * 16;
  const __bf16* qp = QK + ((size_t)(b * SS) + q0 + lr) * QKLD + h * DHD;
  bf16x8 qa[2];
#pragma unroll
  for (int kc = 0; kc < 2; ++kc)
    qa[kc] = *(const bf16x8*)(qp + kc * 32 + 8 * lg);

  // staging geometry: 64x64 bf16 tile (128B rows); 512 threads x 16B = whole
  // tile in ONE global_load_lds. Linear LDS dest + inverse-swizzled source.
  int o0 = tid * 16;
  int row0 = o0 >> 7;                      // 0..63
  int ss0 = ((o0 >> 4) & 7) ^ (row0 & 7);  // source slot
  int lw = wave * 1024;                    // wave-uniform LDS byte base

  const __bf16* kg = QK + (size_t)(b * SS) * QKLD + DD + h * DHD;  // K at +DD
  const __bf16* vg = VT + ((size_t)(b * HH + h) * DHD) * SS;
  const __bf16* Kg0 = kg + (size_t)row0 * QKLD + ss0 * 8;
  const __bf16* Vg0 = vg + (size_t)row0 * SS + ss0 * 8;
  const __bf16* ep = embf + b * SS + 8 * lg;

  // prologue: stage tile 0
  gload_lds16(Kg0, (char*)Ks[0] + lw);
  gload_lds16(Vg0, (char*)Vs[0] + lw);

  f32x4 ctx[4], lacc;
  lacc = (f32x4){0.f, 0.f, 0.f, 0.f};
#pragma unroll
  for (int c = 0; c < 4; ++c) ctx[c] = (f32x4){0.f, 0.f, 0.f, 0.f};
  const float SCALE = 0.03125f;  // 1/sqrt(1024)
  __syncthreads();

  const int NT = SS / 64;
  for (int it = 0; it < NT; ++it) {
    int cur = it & 1;
    int kb = it * 64;
    if (it + 1 < NT) {
      size_t ko = (size_t)(it + 1) * 64 * QKLD;
      int vo = (it + 1) * 64;
      gload_lds16(Kg0 + ko, (char*)Ks[cur ^ 1] + lw);
      gload_lds16(Vg0 + vo, (char*)Vs[cur ^ 1] + lw);
    }
    const char* Kb = (const char*)Ks[cur];
    const char* Vb = (const char*)Vs[cur];
    // ---- QK^T: s[f], D col = key (f*16+lr), row = q (4*lg+r)
    f32x4 s[4];
#pragma unroll
    for (int f = 0; f < 4; ++f) s[f] = (f32x4){0.f, 0.f, 0.f, 0.f};
#pragma unroll
    for (int f = 0; f < 4; ++f) {
      int row = f * 16 + lr;
#pragma unroll
      for (int kc = 0; kc < 2; ++kc) {
        bf16x8 kf = *(const bf16x8*)(Kb + row * 128 + (((kc * 4 + lg) ^ (row & 7)) << 4));
        s[f] = mfma16(qa[kc], kf, s[f]);
      }
    }
    // ---- static softmax: p = exp(s*scale) -> pS (wave-private)
#pragma unroll
    for (int f = 0; f < 4; ++f)
#pragma unroll
      for (int r = 0; r < 4; ++r)
        pS[wave][4 * lg + r][f * 16 + lr] = (__bf16)__expf(s[f][r] * SCALE);
    // em B-frags: k = 8*lg + e -> em[kb + kc*32 + 8*lg + e]
    bf16x8 emf[2];
    emf[0] = *(const bf16x8*)(ep + kb);
    emf[1] = *(const bf16x8*)(ep + kb + 32);
    // ---- re-read P as PV A-frags (same-wave LDS ordering)
    bf16x8 pa[2];
#pragma unroll
    for (int kc = 0; kc < 2; ++kc)
      pa[kc] = *(const bf16x8*)(&pS[wave][lr][kc * 32 + 8 * lg]);
    // ---- denominator via em-broadcast MFMA: lacc[q] += sum_key p*em
    lacc = mfma16(pa[0], emf[0], lacc);
    lacc = mfma16(pa[1], emf[1], lacc);
    // ---- PV: ctx[c] += P[16x64] @ V'[64 keys][16c..16c+15]
#pragma unroll
    for (int c = 0; c < 4; ++c) {
      int row = c * 16 + lr;
#pragma unroll
      for (int kc = 0; kc < 2; ++kc) {
        bf16x8 vf = *(const bf16x8*)(Vb + row * 128 + (((kc * 4 + lg) ^ (row & 7)) << 4));
        ctx[c] = mfma16(pa[kc], vf, ctx[c]);
      }
    }
    __syncthreads();
  }
  // ---- epilogue: divide by denominator, store bf16
  __bf16* op = ctxb + ((size_t)(b * SS) + q0 + 4 * lg) * DD + h * DHD + lr;
#pragma unroll
  for (int r = 0; r < 4; ++r) {
    float inv = 1.0f / lacc[r];
#pragma unroll
    for (int c = 0; c < 4; ++c)
      op[(size_t)r * DD + c * 16] = (__bf16)(ctx[c][r] * inv);
  }
}

// ---------------------------------------------------------------- launcher
extern "C" void kernel_launch(void* const* d_in, const int* in_sizes, int n_in,
                              void* d_out, int out_size, void* d_ws, size_t ws_size,
                              hipStream_t stream) {
  const float* x    = (const float*)d_in[0];
  const float* mask = (const float*)d_in[1];
  const float* Wq   = (const float*)d_in[2];
  const float* Wk   = (const float*)d_in[3];
  const float* Wv   = (const float*)d_in[4];
  const float* Wo   = (const float*)d_in[5];
  const float* bo   = (const float*)d_in[6];
  float* out = (float*)d_out;

  char* ws = (char*)d_ws;
  const size_t MB = 1024 * 1024;
  __bf16* xb   = (__bf16*)(ws + 0);        // 8 MB (reused as ctxb)
  __bf16* WqT  = (__bf16*)(ws + 8 * MB);   // 2 MB (WkT/WvT/WoT contiguous after)
  __bf16* WvT  = (__bf16*)(ws + 12 * MB);
  __bf16* WoT  = (__bf16*)(ws + 14 * MB);
  __bf16* qkb  = (__bf16*)(ws + 16 * MB);  // 16 MB: [4096][2048] fused Q|K
  __bf16* vtb  = (__bf16*)(ws + 32 * MB);  // 8 MB: V'[b,h,d,s] (em-folded)
  __bf16* embf = (__bf16*)(ws + 40 * MB);  // 8 KB
  __bf16* ctxb = xb;

  // 1) prep: cast x, em, 4x W transpose (one launch, 5136 blocks)
  prep_kernel<<<5136, 256, 0, stream>>>(x, xb, mask, embf, Wq, Wk, Wv, Wo, WqT);
  // 2) QK projection + transposed V' projection (one launch, 768 blocks)
  proj_kernel<<<768, 256, 0, stream>>>(xb, WqT, WvT, qkb, vtb, embf);
  // 3) attention (writes ctx bf16 over xb region)
  attn_kernel<<<dim3(16, HH, BB), 512, 0, stream>>>(qkb, vtb, embf, ctxb);
  // 4) output projection (f32 out + bias)
  ogemm_kernel<<<dim3(32, 8), 256, 0, stream>>>(ctxb, WoT, out, bo);
}

// Round 9
// 208.906 us; speedup vs baseline: 2.7017x; 1.0192x over previous
//
#include <hip/hip_runtime.h>
#include <hip/hip_bf16.h>

// Problem constants
#define BB 2
#define SS 2048
#define DD 1024
#define HH 16
#define DHD 64
#define QKLD 2048  // row stride of fused QK buffer

typedef __attribute__((ext_vector_type(8))) __bf16 bf16x8;
typedef __attribute__((ext_vector_type(4))) __bf16 bf16x4;
typedef __attribute__((ext_vector_type(4))) float f32x4;
typedef __attribute__((ext_vector_type(16))) float f32x16;

__device__ __forceinline__ f32x4 mfma16(bf16x8 a, bf16x8 b, f32x4 c) {
  return __builtin_amdgcn_mfma_f32_16x16x32_bf16(a, b, c, 0, 0, 0);
}
__device__ __forceinline__ f32x16 mfma32(bf16x8 a, bf16x8 b, f32x16 c) {
  return __builtin_amdgcn_mfma_f32_32x32x16_bf16(a, b, c, 0, 0, 0);
}
__device__ __forceinline__ void gload_lds16(const void* g, void* l) {
  __builtin_amdgcn_global_load_lds((__attribute__((address_space(1))) const void*)g,
                                   (__attribute__((address_space(3))) void*)l, 16, 0, 0);
}
__device__ __forceinline__ f32x16 zero16() {
  f32x16 z;
#pragma unroll
  for (int i = 0; i < 16; ++i) z[i] = 0.f;
  return z;
}
__device__ __forceinline__ bf16x8 frag4(unsigned a, unsigned b, unsigned c, unsigned d) {
  union { unsigned u[4]; bf16x8 v; } x;
  x.u[0] = a; x.u[1] = b; x.u[2] = c; x.u[3] = d;
  return x.v;
}
// plain-C++ bf16 pair pack (src0 -> low half) — no asm
__device__ __forceinline__ unsigned pack2(float lo, float hi) {
  union { __bf16 h[2]; unsigned u; } x;
  x.h[0] = (__bf16)lo; x.h[1] = (__bf16)hi;
  return x.u;
}

// ---------------------------------------------------------------- prep kernel
// One launch: cast x -> bf16 (blocks 0..4095), em = exp(mask) (4096..4111),
// all four W [K,N] fp32 -> WT [N,K] bf16 (4112..5135).
__global__ __launch_bounds__(256) void prep_kernel(
    const float* __restrict__ x, __bf16* __restrict__ xb,
    const float* __restrict__ mask, __bf16* __restrict__ embf,
    const float* __restrict__ Wq, const float* __restrict__ Wk,
    const float* __restrict__ Wv, const float* __restrict__ Wo,
    __bf16* __restrict__ WTbase) {
  __shared__ __bf16 t[64][65];
  int id = blockIdx.x, tid = threadIdx.x;
  if (id < 4096) {
    int i = id * 256 + tid;
    float4 f = ((const float4*)x)[i];
    bf16x4 o;
    o[0] = (__bf16)f.x; o[1] = (__bf16)f.y; o[2] = (__bf16)f.z; o[3] = (__bf16)f.w;
    *(bf16x4*)(xb + (size_t)i * 4) = o;
    return;
  }
  if (id < 4112) {
    int j = (id - 4096) * 256 + tid;
    embf[j] = (__bf16)__expf(mask[j]);
    return;
  }
  int idx = id - 4112;
  int z = idx >> 8, rem = idx & 255;
  const float* W = (z == 0) ? Wq : (z == 1) ? Wk : (z == 2) ? Wv : Wo;
  __bf16* WT = WTbase + ((size_t)z << 20);
  int c0 = (rem & 15) * 64, r0 = (rem >> 4) * 64;
  {
    int rr = tid >> 4, cg = tid & 15;
#pragma unroll
    for (int it = 0; it < 4; ++it) {
      int r = rr + it * 16;
      float4 f = *(const float4*)(W + (size_t)(r0 + r) * DD + c0 + cg * 4);
      t[r][cg * 4 + 0] = (__bf16)f.x;
      t[r][cg * 4 + 1] = (__bf16)f.y;
      t[r][cg * 4 + 2] = (__bf16)f.z;
      t[r][cg * 4 + 3] = (__bf16)f.w;
    }
  }
  __syncthreads();
  {
    int sg = tid & 7;
#pragma unroll
    for (int it = 0; it < 2; ++it) {
      int wc = (tid >> 3) + it * 32;
      __bf16 tmp[8];
#pragma unroll
      for (int e = 0; e < 8; ++e) tmp[e] = t[sg * 8 + e][wc];
      bf16x8 o;
#pragma unroll
      for (int e = 0; e < 8; ++e) o[e] = tmp[e];
      *(bf16x8*)(WT + (size_t)(c0 + wc) * DD + r0 + sg * 8) = o;
    }
  }
}

// ---------------------------------------------------------------- GEMM body
// C[M,N] = A[M,K] @ BT[N,K]^T. 128x128 tile, BK=32, 4 waves x (64x64).
// MODE 0: bf16 C. MODE 1: f32 C + bias. MODE 2: write C'[dh][s]*em[s] into
//         vt[b,h,d,s] (transposed V-projection with folded exp(mask)).
template <int MODE>
__device__ __forceinline__ void gemm_body(
    char* AsB, char* BsB, int bx, int by,
    const __bf16* __restrict__ A, const __bf16* __restrict__ BT,
    float* __restrict__ Cf, __bf16* __restrict__ Cb,
    const float* __restrict__ bias, const __bf16* __restrict__ embf,
    int M, int N, int K) {
  int tid = threadIdx.x;
  int lane = tid & 63, wave = tid >> 6;
  int lr = lane & 15, lg = lane >> 4;
  int wr = wave >> 1, wc = wave & 1;
  int m0 = bx * 128, n0 = by * 128;

  int o0 = wave * 1024 + lane * 16;
  int r0i = o0 >> 6, s0i = ((o0 >> 4) & 3) ^ (r0i & 3);
  int o1 = o0 + 4096;
  int r1i = o1 >> 6, s1i = ((o1 >> 4) & 3) ^ (r1i & 3);

  const __bf16* Ag0 = A + (size_t)(m0 + r0i) * K + s0i * 8;
  const __bf16* Ag1 = A + (size_t)(m0 + r1i) * K + s1i * 8;
  const __bf16* Bg0 = BT + (size_t)(n0 + r0i) * K + s0i * 8;
  const __bf16* Bg1 = BT + (size_t)(n0 + r1i) * K + s1i * 8;
  int lb0 = wave * 1024, lb1 = wave * 1024 + 4096;

  f32x4 acc[4][4];
#pragma unroll
  for (int m = 0; m < 4; ++m)
#pragma unroll
    for (int n = 0; n < 4; ++n) acc[m][n] = (f32x4){0.f, 0.f, 0.f, 0.f};

  gload_lds16(Ag0, AsB + lb0);
  gload_lds16(Ag1, AsB + lb1);
  gload_lds16(Bg0, BsB + lb0);
  gload_lds16(Bg1, BsB + lb1);
  __syncthreads();

  int NK = K >> 5;
  for (int it = 0; it < NK; ++it) {
    int cur = it & 1;
    if (it + 1 < NK) {
      int ko = (it + 1) * 32;
      char* An = AsB + (cur ^ 1) * 8192;
      char* Bn = BsB + (cur ^ 1) * 8192;
      gload_lds16(Ag0 + ko, An + lb0);
      gload_lds16(Ag1 + ko, An + lb1);
      gload_lds16(Bg0 + ko, Bn + lb0);
      gload_lds16(Bg1 + ko, Bn + lb1);
    }
    const char* Ab = AsB + cur * 8192;
    const char* Bb = BsB + cur * 8192;
    bf16x8 af[4], bfr[4];
#pragma unroll
    for (int m = 0; m < 4; ++m) {
      int row = wr * 64 + m * 16 + lr;
      af[m] = *(const bf16x8*)(Ab + row * 64 + ((lg ^ (row & 3)) << 4));
    }
#pragma unroll
    for (int n = 0; n < 4; ++n) {
      int row = wc * 64 + n * 16 + lr;
      bfr[n] = *(const bf16x8*)(Bb + row * 64 + ((lg ^ (row & 3)) << 4));
    }
#pragma unroll
    for (int m = 0; m < 4; ++m)
#pragma unroll
      for (int n = 0; n < 4; ++n) acc[m][n] = mfma16(af[m], bfr[n], acc[m][n]);
    __syncthreads();
  }

  // epilogue: D layout col = lane&15, row = 4*(lane>>4)+reg
#pragma unroll
  for (int m = 0; m < 4; ++m) {
#pragma unroll
    for (int n = 0; n < 4; ++n) {
      int cc = n0 + wc * 64 + n * 16 + lr;
      float ef = 0.f;
      if constexpr (MODE == 2) ef = (float)embf[cc];
#pragma unroll
      for (int r = 0; r < 4; ++r) {
        int rr = m0 + wr * 64 + m * 16 + 4 * lg + r;
        if constexpr (MODE == 1) {
          Cf[(size_t)rr * N + cc] = acc[m][n][r] + bias[cc];
        } else if constexpr (MODE == 0) {
          Cb[(size_t)rr * N + cc] = (__bf16)acc[m][n][r];
        } else {
          // rr = dh (0..1023), cc = s-global (0..4095)
          int bb2 = cc >> 11, sl = cc & (SS - 1);
          int hh = rr >> 6, dd2 = rr & 63;
          Cb[(((size_t)bb2 * HH + hh) * DHD + dd2) * SS + sl] =
              (__bf16)(acc[m][n][r] * ef);
        }
      }
    }
  }
}

// ------------- one launch: QK projection (blocks 0..511) + V' (512..767)
__global__ __launch_bounds__(256, 2) void proj_kernel(
    const __bf16* __restrict__ xb, const __bf16* __restrict__ WqT,
    const __bf16* __restrict__ WvT, __bf16* __restrict__ qkb,
    __bf16* __restrict__ vtb, const __bf16* __restrict__ embf) {
  __shared__ __bf16 As[2][128 * 32];
  __shared__ __bf16 Bs[2][128 * 32];
  int id = blockIdx.x;
  if (id < 512) {
    gemm_body<0>((char*)As, (char*)Bs, id & 31, id >> 5,
                 xb, WqT, nullptr, qkb, nullptr, nullptr, 4096, 2048, 1024);
  } else {
    int i2 = id - 512;
    gemm_body<2>((char*)As, (char*)Bs, i2 & 7, i2 >> 3,
                 WvT, xb, nullptr, vtb, nullptr, embf, 1024, 4096, 1024);
  }
}

// ------------- output projection (f32 + bias)
__global__ __launch_bounds__(256, 2) void ogemm_kernel(
    const __bf16* __restrict__ ctxb, const __bf16* __restrict__ WoT,
    float* __restrict__ out, const float* __restrict__ bo) {
  __shared__ __bf16 As[2][128 * 32];
  __shared__ __bf16 Bs[2][128 * 32];
  gemm_body<1>((char*)As, (char*)Bs, blockIdx.x, blockIdx.y,
               ctxb, WoT, out, nullptr, bo, nullptr, 4096, 1024, 1024);
}

// ---------------------------------------------------------------- attention
// grid (S/128, H, B), 4 waves x 32 q-rows. 32x32x16 swapped QK^T (lane holds
// P for its q-row = lane&31) -> ZERO P-LDS traffic. Static softmax (mask
// folded as em=exp(mask) into V' + em-MFMA denominator). P redistribution
// lo/hi half exchange via __shfl_xor(.,32) + select (fully specified
// primitives; no permlane/cvt_pk asm).
__global__ __launch_bounds__(256, 2) void attn_kernel(
    const __bf16* __restrict__ QK, const __bf16* __restrict__ VT,
    const __bf16* __restrict__ embf, __bf16* __restrict__ ctxb) {
  __shared__ __bf16 Ks[2][64 * 64];
  __shared__ __bf16 Vs[2][64 * 64];

  int h = blockIdx.y, b = blockIdx.z;
  int tid = threadIdx.x;
  int wave = tid >> 6, lane = tid & 63;
  int l31 = lane & 31, hi = lane >> 5;
  int rx = l31 & 7;

  int q0 = blockIdx.x * 128 + wave * 32;
  // Q B-frags: B[k][n=q=l31], k = 8*hi+e, d = 16*kc + k
  const __bf16* qp = QK + ((size_t)(b * SS) + q0 + l31) * QKLD + h * DHD + 8 * hi;
  bf16x8 qfrag[4];
#pragma unroll
  for (int kc = 0; kc < 4; ++kc) qfrag[kc] = *(const bf16x8*)(qp + 16 * kc);

  // staging geometry: 64x64 bf16 tile (128B rows), 2 issues/thread,
  // linear LDS dest + inverse-swizzled global source (rule #21)
  int o0 = tid * 16;
  int row0 = o0 >> 7;                      // 0..31
  int ss0 = ((o0 >> 4) & 7) ^ (row0 & 7);  // source slot
  int lw0 = wave * 1024, lw1 = wave * 1024 + 4096;

  const __bf16* kg = QK + (size_t)(b * SS) * QKLD + DD + h * DHD;  // K at +DD
  const __bf16* vg = VT + ((size_t)(b * HH + h) * DHD) * SS;
  const __bf16* Kg0 = kg + (size_t)row0 * QKLD + ss0 * 8;
  const __bf16* Kg1 = kg + (size_t)(row0 + 32) * QKLD + ss0 * 8;
  const __bf16* Vg0 = vg + (size_t)row0 * SS + ss0 * 8;
  const __bf16* Vg1 = vg + (size_t)(row0 + 32) * SS + ss0 * 8;
  const __bf16* ep = embf + b * SS + 8 * hi;

  // prologue: stage tile 0
  gload_lds16(Kg0, (char*)Ks[0] + lw0);
  gload_lds16(Kg1, (char*)Ks[0] + lw1);
  gload_lds16(Vg0, (char*)Vs[0] + lw0);
  gload_lds16(Vg1, (char*)Vs[0] + lw1);

  f32x16 ctx0 = zero16(), ctx1 = zero16(), lacc = zero16();
  const float SCALE = 0.03125f;  // 1/sqrt(1024)
  __syncthreads();

  const int NT = SS / 64;
  for (int it = 0; it < NT; ++it) {
    int cur = it & 1;
    int kb = it * 64;
    if (it + 1 < NT) {
      size_t ko = (size_t)(it + 1) * 64 * QKLD;
      int vo = (it + 1) * 64;
      gload_lds16(Kg0 + ko, (char*)Ks[cur ^ 1] + lw0);
      gload_lds16(Kg1 + ko, (char*)Ks[cur ^ 1] + lw1);
      gload_lds16(Vg0 + vo, (char*)Vs[cur ^ 1] + lw0);
      gload_lds16(Vg1 + vo, (char*)Vs[cur ^ 1] + lw1);
    }
    // em B-frags: element e -> em[kb + 16*q2 + 8*hi + e] (uniform in l31)
    bf16x8 emf[4];
#pragma unroll
    for (int q2 = 0; q2 < 4; ++q2) emf[q2] = *(const bf16x8*)(ep + kb + 16 * q2);

    const char* Kb = (const char*)Ks[cur];
    const char* Vb = (const char*)Vs[cur];
#pragma unroll
    for (int kc32 = 0; kc32 < 2; ++kc32) {
      // ---- QK^T (swapped): D[key][q]; A=K (row=key=kc32*32+l31), B=Q (col=q)
      f32x16 sc = zero16();
#pragma unroll
      for (int kc = 0; kc < 4; ++kc) {
        bf16x8 kf = *(const bf16x8*)(Kb + (kc32 * 32 + l31) * 128 +
                                     ((((kc << 1) + hi) ^ rx) << 4));
        sc = mfma32(kf, qfrag[kc], sc);
      }
      // ---- static softmax: p = exp(s*scale); reg i -> key (i&3)+8*(i>>2)+4*hi
      // pack pairs: pk[i2] = keys {2*(i2&1) + 8*(i2>>1) + 4*hi + {0,1}}
      unsigned pk[8];
#pragma unroll
      for (int i2 = 0; i2 < 8; ++i2)
        pk[i2] = pack2(__expf(sc[2 * i2] * SCALE), __expf(sc[2 * i2 + 1] * SCALE));
      // ---- redistribute lo/hi halves via shfl_xor(32) + select.
      // A-frag word j needs keys 8*hi + 2j (+16 for pf1's second half).
      unsigned sx0 = __shfl_xor(pk[0], 32, 64);
      unsigned sx1 = __shfl_xor(pk[1], 32, 64);
      unsigned sx2 = __shfl_xor(pk[2], 32, 64);
      unsigned sx3 = __shfl_xor(pk[3], 32, 64);
      unsigned sx4 = __shfl_xor(pk[4], 32, 64);
      unsigned sx5 = __shfl_xor(pk[5], 32, 64);
      unsigned sx6 = __shfl_xor(pk[6], 32, 64);
      unsigned sx7 = __shfl_xor(pk[7], 32, 64);
      unsigned w0 = hi ? sx2 : pk[0];  // keys 8hi+{0,1}
      unsigned w1 = hi ? sx3 : pk[1];  // keys 8hi+{2,3}
      unsigned w2 = hi ? pk[2] : sx0;  // keys 8hi+{4,5}
      unsigned w3 = hi ? pk[3] : sx1;  // keys 8hi+{6,7}
      unsigned w4 = hi ? sx6 : pk[4];  // keys 16+8hi+{0,1}
      unsigned w5 = hi ? sx7 : pk[5];  // keys 16+8hi+{2,3}
      unsigned w6 = hi ? pk[6] : sx4;  // keys 16+8hi+{4,5}
      unsigned w7 = hi ? pk[7] : sx5;  // keys 16+8hi+{6,7}
      bf16x8 pf0 = frag4(w0, w1, w2, w3);  // keys kc32*32 + 0..15
      bf16x8 pf1 = frag4(w4, w5, w6, w7);  // keys kc32*32 + 16..31
      // ---- denominator via em-broadcast MFMA: lacc[q] += sum_key p*em
      lacc = mfma32(pf0, emf[kc32 * 2 + 0], lacc);
      lacc = mfma32(pf1, emf[kc32 * 2 + 1], lacc);
      // ---- PV: D[q][d] += P[q][keys] @ V'[d][keys]^T  (B col = d = l31)
      {
        bf16x8 v00 = *(const bf16x8*)(Vb + (l31)*128 + ((((kc32 << 2) + 0 + hi) ^ rx) << 4));
        ctx0 = mfma32(pf0, v00, ctx0);
        bf16x8 v01 = *(const bf16x8*)(Vb + (l31)*128 + ((((kc32 << 2) + 2 + hi) ^ rx) << 4));
        ctx0 = mfma32(pf1, v01, ctx0);
        bf16x8 v10 = *(const bf16x8*)(Vb + (32 + l31) * 128 + ((((kc32 << 2) + 0 + hi) ^ rx) << 4));
        ctx1 = mfma32(pf0, v10, ctx1);
        bf16x8 v11 = *(const bf16x8*)(Vb + (32 + l31) * 128 + ((((kc32 << 2) + 2 + hi) ^ rx) << 4));
        ctx1 = mfma32(pf1, v11, ctx1);
      }
    }
    __syncthreads();
  }
  // ---- epilogue: ctx/l; reg i -> q = (i&3)+8*(i>>2)+4*hi, d = dc*32+l31
#pragma unroll
  for (int i = 0; i < 16; ++i) {
    float inv = 1.0f / lacc[i];
    int q = (i & 3) + 8 * (i >> 2) + 4 * hi;
    __bf16* op = ctxb + ((size_t)(b * SS) + q0 + q) * DD + h * DHD + l31;
    op[0] = (__bf16)(ctx0[i] * inv);
    op[32] = (__bf16)(ctx1[i] * inv);
  }
}

// ---------------------------------------------------------------- launcher
extern "C" void kernel_launch(void* const* d_in, const int* in_sizes, int n_in,
                              void* d_out, int out_size, void* d_ws, size_t ws_size,
                              hipStream_t stream) {
  const float* x    = (const float*)d_in[0];
  const float* mask = (const float*)d_in[1];
  const float* Wq   = (const float*)d_in[2];
  const float* Wk   = (const float*)d_in[3];
  const float* Wv   = (const float*)d_in[4];
  const float* Wo   = (const float*)d_in[5];
  const float* bo   = (const float*)d_in[6];
  float* out = (float*)d_out;

  char* ws = (char*)d_ws;
  const size_t MB = 1024 * 1024;
  __bf16* xb   = (__bf16*)(ws + 0);        // 8 MB (reused as ctxb)
  __bf16* WqT  = (__bf16*)(ws + 8 * MB);   // 2 MB (WkT/WvT/WoT contiguous after)
  __bf16* WvT  = (__bf16*)(ws + 12 * MB);
  __bf16* WoT  = (__bf16*)(ws + 14 * MB);
  __bf16* qkb  = (__bf16*)(ws + 16 * MB);  // 16 MB: [4096][2048] fused Q|K
  __bf16* vtb  = (__bf16*)(ws + 32 * MB);  // 8 MB: V'[b,h,d,s] (em-folded)
  __bf16* embf = (__bf16*)(ws + 40 * MB);  // 8 KB
  __bf16* ctxb = xb;

  // 1) prep: cast x, em, 4x W transpose (one launch, 5136 blocks)
  prep_kernel<<<5136, 256, 0, stream>>>(x, xb, mask, embf, Wq, Wk, Wv, Wo, WqT);
  // 2) QK projection + transposed V' projection (one launch, 768 blocks)
  proj_kernel<<<768, 256, 0, stream>>>(xb, WqT, WvT, qkb, vtb, embf);
  // 3) attention (writes ctx bf16 over xb region)
  attn_kernel<<<dim3(16, HH, BB), 256, 0, stream>>>(qkb, vtb, embf, ctxb);
  // 4) output projection (f32 out + bias)
  ogemm_kernel<<<dim3(32, 8), 256, 0, stream>>>(ctxb, WoT, out, bo);
}